// Round 2
// baseline (948.475 us; speedup 1.0000x reference)
//
#include <hip/hip_runtime.h>

// ---------------- problem constants ----------------
#define NPTS 100000
#define KNN  16

// workspace layout (float offsets)
#define Y_OFF    0            // y = x@w03+b03 : NPTS*64
#define BLWS_OFF 6400000      // symmetrized blW: 136 pairs x 16 o
#define C2AT_OFF 6402176      // c2a transposed+BN-folded: 64 x 32
#define T2A_OFF  6404224      // 64
#define C2BF_OFF 6404288      // c2b BN-folded: 64 x 8
#define T2B_OFF  6404800      // 8
#define AF_OFF   6404808      // linear_p folded 3x3
#define CF_OFF   6404817      // 3

// output layout (float offsets): (out, xk, knn_idx, p_r)
#define OUT_OFF  0
#define XK_OFF   6400000
#define IDXF_OFF 108800000
#define PR_OFF   110400000

#define EPSBN 1e-5f

// LDS weight arena (float offsets within lw[]); float4 indices in comments
// W01   : 0    .. 1072   (67 rows x 16)   q-base 0, row cc -> 4*cc
// BLWS  : 1072 .. 3248   (136 x 16)       q-base 268 + pidx*4
// C2AT  : 3248 .. 5296   (64 x 32)        q-base 812 + c*8
// C2BF  : 5296 .. 5808   (64 x 8)         q-base 1324 + c*2
// LP2W  : 5808 .. 6000   (3 x 64)         q-base 1452 + d*16
// LP2B  : 6000 .. 6064                    q-base 1500
// C2CW  : 6064 .. 6128   (8 x 8)
// C2CB  : 6128 .. 6136
// T2A   : 6136 .. 6200
// T2B   : 6200 .. 6208
// BLB   : 6208 .. 6224                    q-base 1552
// B01   : 6224 .. 6240                    q-base 1556
// AF    : 6240 .. 6249
// CF    : 6249 .. 6252
#define LW_SIZE 6252

__device__ __forceinline__ float4 f4fma(float a, float4 b, float4 c) {
    c.x = fmaf(a, b.x, c.x); c.y = fmaf(a, b.y, c.y);
    c.z = fmaf(a, b.z, c.z); c.w = fmaf(a, b.w, c.w);
    return c;
}
__device__ __forceinline__ float4 f4fma4(float4 a, float4 b, float4 c) {
    c.x = fmaf(a.x, b.x, c.x); c.y = fmaf(a.y, b.y, c.y);
    c.z = fmaf(a.z, b.z, c.z); c.w = fmaf(a.w, b.w, c.w);
    return c;
}

// ---------------- prep: fold BNs, symmetrize blW ----------------
__global__ __launch_bounds__(256) void prep_small(
    const float* __restrict__ blW,
    const float* __restrict__ c2a_w, const float* __restrict__ g2a, const float* __restrict__ b2a,
    const float* __restrict__ m2a, const float* __restrict__ v2a,
    const float* __restrict__ c2b_w, const float* __restrict__ g2b, const float* __restrict__ b2b,
    const float* __restrict__ m2b, const float* __restrict__ v2b,
    const float* __restrict__ lp1_w, const float* __restrict__ lp1_b,
    const float* __restrict__ bnp_g, const float* __restrict__ bnp_b,
    const float* __restrict__ bnp_m, const float* __restrict__ bnp_v,
    float* __restrict__ ws)
{
    const int t = threadIdx.x;
    float* blWs = ws + BLWS_OFF;
    for (int u = t; u < 136 * 16; u += 256) {
        const int pidx = u >> 4, o = u & 15;
        int i = 0, rem = pidx;
        while (rem >= 16 - i) { rem -= 16 - i; i++; }
        const int j = i + rem;
        float v = blW[o * 256 + i * 16 + j];
        if (j > i) v += blW[o * 256 + j * 16 + i];
        blWs[pidx * 16 + o] = v;
    }
    float* c2aT = ws + C2AT_OFF;
    for (int u = t; u < 64 * 32; u += 256) {
        const int c = u >> 5, d = u & 31;
        const float f = g2a[c] / sqrtf(v2a[c] + EPSBN);
        c2aT[c * 32 + d] = c2a_w[d * 64 + c] * f;
    }
    if (t < 64) {
        const float f = g2a[t] / sqrtf(v2a[t] + EPSBN);
        (ws + T2A_OFF)[t] = b2a[t] - m2a[t] * f;
    }
    float* c2bf = ws + C2BF_OFF;
    for (int u = t; u < 64 * 8; u += 256) {
        const int s = u & 7;
        const float f = g2b[s] / sqrtf(v2b[s] + EPSBN);
        c2bf[u] = c2b_w[u] * f;
    }
    if (t < 8) {
        const float f = g2b[t] / sqrtf(v2b[t] + EPSBN);
        (ws + T2B_OFF)[t] = b2b[t] - m2b[t] * f;
    }
    if (t < 9) {
        const int j = t % 3;
        const float f = bnp_g[j] / sqrtf(bnp_v[j] + EPSBN);
        (ws + AF_OFF)[t] = lp1_w[t] * f;
    }
    if (t < 3) {
        const float f = bnp_g[t] / sqrtf(bnp_v[t] + EPSBN);
        (ws + CF_OFF)[t] = (lp1_b[t] - bnp_m[t]) * f + bnp_b[t];
    }
}

// ---------------- y = x @ w03 + b03  (one thread per (n, c4)) ----------------
__global__ __launch_bounds__(256) void y_gemm(
    const float* __restrict__ x, const float* __restrict__ w03,
    const float* __restrict__ b03, float* __restrict__ ws)
{
    const int tid = blockIdx.x * 256 + threadIdx.x;
    const int n = tid >> 4, c4 = tid & 15;
    const float4* __restrict__ x4 = (const float4*)x;
    const float4* __restrict__ w4 = (const float4*)w03;
    float4 acc = ((const float4*)b03)[c4];
    #pragma unroll 4
    for (int d4 = 0; d4 < 16; d4++) {
        const float4 xq = x4[n * 16 + d4];
        const float xs[4] = {xq.x, xq.y, xq.z, xq.w};
        #pragma unroll
        for (int e = 0; e < 4; e++) {
            const float4 wq = w4[(d4 * 4 + e) * 16 + c4];
            acc.x = fmaf(xs[e], wq.x, acc.x);
            acc.y = fmaf(xs[e], wq.y, acc.y);
            acc.z = fmaf(xs[e], wq.z, acc.z);
            acc.w = fmaf(xs[e], wq.w, acc.w);
        }
    }
    ((float4*)(ws + Y_OFF))[n * 16 + c4] = acc;
}

// ---------------- main fused kernel: one thread per (n,k) ----------------
__global__ __launch_bounds__(256) void pm_main(
    const float* __restrict__ p, const float* __restrict__ x,
    const int* __restrict__ knn,
    const float* __restrict__ w01, const float* __restrict__ b01,
    const float* __restrict__ blB,
    const float* __restrict__ lp2_w, const float* __restrict__ lp2_b,
    const float* __restrict__ c2c_w, const float* __restrict__ c2c_b,
    const float* __restrict__ ws, float* __restrict__ out)
{
    __shared__ float lw[LW_SIZE];        // 25.0 KB weight arena (broadcast reads)
    __shared__ float meta[256][12];      // 12 KB per-(n,k) state for phase-5 remap

    const int tid = blockIdx.x * 256 + threadIdx.x;
    const int n = tid >> 4;
    const int k = tid & 15;
    const int idx = knn[tid];

    // ---- issue the random x-row gather immediately (latency hides under staging) ----
    const float4* __restrict__ x4g = (const float4*)x;
    float4 xr[16];
    #pragma unroll
    for (int q = 0; q < 16; q++) xr[q] = x4g[idx * 16 + q];

    const float prx = p[idx * 3 + 0] - p[n * 3 + 0];
    const float pry = p[idx * 3 + 1] - p[n * 3 + 1];
    const float prz = p[idx * 3 + 2] - p[n * 3 + 2];

    // ---- stage all small weights into LDS (once per block) ----
    {
        const int t = threadIdx.x;
        for (int u = t; u < 1072; u += 256) lw[u] = w01[u];
        for (int u = t; u < 2176; u += 256) lw[1072 + u] = ws[BLWS_OFF + u];
        for (int u = t; u < 2048; u += 256) lw[3248 + u] = ws[C2AT_OFF + u];
        for (int u = t; u < 512; u += 256)  lw[5296 + u] = ws[C2BF_OFF + u];
        if (t < 192) lw[5808 + t] = lp2_w[t];
        else         lw[6000 + (t - 192)] = lp2_b[t - 192];
        if (t < 64)       lw[6064 + t] = c2c_w[t];
        else if (t < 72)  lw[6128 + (t - 64)] = c2c_b[t - 64];
        else if (t < 136) lw[6136 + (t - 72)] = ws[T2A_OFF + (t - 72)];
        else if (t < 144) lw[6200 + (t - 136)] = ws[T2B_OFF + (t - 136)];
        else if (t < 160) lw[6208 + (t - 144)] = blB[t - 144];
        else if (t < 176) lw[6224 + (t - 160)] = b01[t - 160];
        else if (t < 185) lw[6240 + (t - 176)] = ws[AF_OFF + (t - 176)];
        else if (t < 188) lw[6249 + (t - 185)] = ws[CF_OFF + (t - 185)];
    }

    out[IDXF_OFF + tid] = (float)idx;
    out[PR_OFF + tid * 3 + 0] = prx;
    out[PR_OFF + tid * 3 + 1] = pry;
    out[PR_OFF + tid * 3 + 2] = prz;

    __syncthreads();
    const float4* __restrict__ lw4 = (const float4*)lw;

    // ---- phase 1: h = relu([p_r, x[idx]] @ w01 + b01) ----
    float4 hq[4];
    #pragma unroll
    for (int t4 = 0; t4 < 4; t4++) hq[t4] = lw4[1556 + t4];   // b01
    {
        const float pr3[3] = {prx, pry, prz};
        #pragma unroll
        for (int c = 0; c < 3; c++) {
            const float xv = pr3[c];
            #pragma unroll
            for (int t4 = 0; t4 < 4; t4++) hq[t4] = f4fma(xv, lw4[c * 4 + t4], hq[t4]);
        }
    }
    #pragma unroll
    for (int q = 0; q < 16; q++) {
        const float xs[4] = {xr[q].x, xr[q].y, xr[q].z, xr[q].w};
        #pragma unroll
        for (int e = 0; e < 4; e++) {
            const int cc = 3 + q * 4 + e;
            const float xv = xs[e];
            #pragma unroll
            for (int t4 = 0; t4 < 4; t4++) hq[t4] = f4fma(xv, lw4[cc * 4 + t4], hq[t4]);
        }
    }
    float h[16];
    #pragma unroll
    for (int t4 = 0; t4 < 4; t4++) {
        h[4 * t4 + 0] = fmaxf(hq[t4].x, 0.f);
        h[4 * t4 + 1] = fmaxf(hq[t4].y, 0.f);
        h[4 * t4 + 2] = fmaxf(hq[t4].z, 0.f);
        h[4 * t4 + 3] = fmaxf(hq[t4].w, 0.f);
    }

    // ---- phase 2: energy[o] = sum_{i<=j} h_i h_j * blWs[(i,j)][o] + blB ----
    float4 e4[4];
    #pragma unroll
    for (int t4 = 0; t4 < 4; t4++) e4[t4] = lw4[1552 + t4];   // blB
    {
        int pidx = 0;
        #pragma unroll
        for (int i = 0; i < 16; i++) {
            #pragma unroll
            for (int j = i; j < 16; j++) {
                const float u = h[i] * h[j];
                const int qb = 268 + pidx * 4;
                #pragma unroll
                for (int t4 = 0; t4 < 4; t4++) e4[t4] = f4fma(u, lw4[qb + t4], e4[t4]);
                pidx++;
            }
        }
    }

    // ---- phase 3: folded linear_p; shrink from rank-1 p_embed ----
    float pe0, pe1, pe2;
    {
        const float* Af = lw + 6240;
        const float* cf = lw + 6249;
        pe0 = fmaxf(fmaf(prx, Af[0], fmaf(pry, Af[3], fmaf(prz, Af[6], cf[0]))), 0.f);
        pe1 = fmaxf(fmaf(prx, Af[1], fmaf(pry, Af[4], fmaf(prz, Af[7], cf[1]))), 0.f);
        pe2 = fmaxf(fmaf(prx, Af[2], fmaf(pry, Af[5], fmaf(prz, Af[8], cf[2]))), 0.f);
    }
    float4 sh4[4];
    #pragma unroll
    for (int t4 = 0; t4 < 4; t4++) {
        float4 s = make_float4(0.f, 0.f, 0.f, 0.f);
        #pragma unroll
        for (int a = 0; a < 4; a++) {
            const int o = a * 4 + t4;
            float4 v = lw4[1500 + o];                 // lp2_b quad
            v = f4fma(pe0, lw4[1452 + o], v);
            v = f4fma(pe1, lw4[1468 + o], v);
            v = f4fma(pe2, lw4[1484 + o], v);
            s.x += v.x; s.y += v.y; s.z += v.z; s.w += v.w;
        }
        sh4[t4] = s;
    }

    // ---- phase 4: c2a(BN,relu) -> c2b(BN,relu) -> c2c -> softmax over k ----
    float4 s4[2];
    s4[0] = lw4[1550]; s4[1] = lw4[1551];             // t2b (floats 6200..6207)
    {
        #pragma unroll 2
        for (int c = 0; c < 64; c++) {
            const int qb = 812 + c * 8;
            float4 a4 = make_float4(0.f, 0.f, 0.f, 0.f);
            #pragma unroll
            for (int q = 0; q < 4; q++) a4 = f4fma4(e4[q], lw4[qb + q], a4);
            #pragma unroll
            for (int q = 0; q < 4; q++) a4 = f4fma4(sh4[q], lw4[qb + 4 + q], a4);
            const float hc = fmaxf(a4.x + a4.y + a4.z + a4.w + lw[6136 + c], 0.f);
            const int bb = 1324 + c * 2;
            s4[0] = f4fma(hc, lw4[bb], s4[0]);
            s4[1] = f4fma(hc, lw4[bb + 1], s4[1]);
        }
    }
    float h2b[8];
    h2b[0] = fmaxf(s4[0].x, 0.f); h2b[1] = fmaxf(s4[0].y, 0.f);
    h2b[2] = fmaxf(s4[0].z, 0.f); h2b[3] = fmaxf(s4[0].w, 0.f);
    h2b[4] = fmaxf(s4[1].x, 0.f); h2b[5] = fmaxf(s4[1].y, 0.f);
    h2b[6] = fmaxf(s4[1].z, 0.f); h2b[7] = fmaxf(s4[1].w, 0.f);
    float2 l2[4];
    {
        const float2* cb2 = (const float2*)(lw + 6128);
        #pragma unroll
        for (int t = 0; t < 4; t++) l2[t] = cb2[t];
        const float2* c2c2 = (const float2*)(lw + 6064);
        #pragma unroll
        for (int s = 0; s < 8; s++) {
            const float hv = h2b[s];
            #pragma unroll
            for (int t = 0; t < 4; t++) {
                const float2 w2 = c2c2[s * 4 + t];
                l2[t].x = fmaf(hv, w2.x, l2[t].x);
                l2[t].y = fmaf(hv, w2.y, l2[t].y);
            }
        }
    }
    float wgt[8];
    #pragma unroll
    for (int s = 0; s < 8; s++) {
        const float l = (s & 1) ? l2[s >> 1].y : l2[s >> 1].x;
        float m = l;
        m = fmaxf(m, __shfl_xor(m, 1, 64));
        m = fmaxf(m, __shfl_xor(m, 2, 64));
        m = fmaxf(m, __shfl_xor(m, 4, 64));
        m = fmaxf(m, __shfl_xor(m, 8, 64));
        const float ex = __expf(l - m);
        float sm = ex;
        sm += __shfl_xor(sm, 1, 64);
        sm += __shfl_xor(sm, 2, 64);
        sm += __shfl_xor(sm, 4, 64);
        sm += __shfl_xor(sm, 8, 64);
        wgt[s] = ex / sm;
    }

    // ---- phase 4.5: publish per-(n,k) state ----
    {
        float4* m4 = (float4*)&meta[threadIdx.x][0];
        m4[0] = make_float4(wgt[0], wgt[1], wgt[2], wgt[3]);
        m4[1] = make_float4(wgt[4], wgt[5], wgt[6], wgt[7]);
        m4[2] = make_float4(pe0, pe1, pe2, __int_as_float(idx));
    }
    __syncthreads();

    // ---- phase 5 (remapped, batched loads): lane l owns (k = j*4 + l>>4, c4 = l&15) ----
    {
        const int lane = threadIdx.x & 63;
        const int waveBase = threadIdx.x & 192;
        const int c4 = lane & 15;
        const int kh = lane >> 4;
        const float4 lw0 = lw4[1452 + c4];
        const float4 lw1 = lw4[1468 + c4];
        const float4 lw2 = lw4[1484 + c4];
        const float4 lb  = lw4[1500 + c4];
        const float4* __restrict__ y4 = (const float4*)(ws + Y_OFF);
        const int nBase = blockIdx.x * 16 + (waveBase >> 4);
        const int wsel = c4 & 1;
        for (int g = 0; g < 4; g++) {
            const int n_g = nBase + g;
            float4 wv[4], pv[4];
            #pragma unroll
            for (int j = 0; j < 4; j++) {
                const int s = waveBase + g * 16 + j * 4 + kh;
                wv[j] = *((const float4*)&meta[s][0] + wsel);
                pv[j] = *((const float4*)&meta[s][0] + 2);
            }
            float4 yv[4];
            #pragma unroll
            for (int j = 0; j < 4; j++)
                yv[j] = y4[__float_as_int(pv[j].w) * 16 + c4];
            float4 racc = make_float4(0.f, 0.f, 0.f, 0.f);
            #pragma unroll
            for (int j = 0; j < 4; j++) {
                float4 r;
                r.x = (yv[j].x + fmaf(pv[j].x, lw0.x, fmaf(pv[j].y, lw1.x, fmaf(pv[j].z, lw2.x, lb.x)))) * wv[j].x;
                r.y = (yv[j].y + fmaf(pv[j].x, lw0.y, fmaf(pv[j].y, lw1.y, fmaf(pv[j].z, lw2.y, lb.y)))) * wv[j].y;
                r.z = (yv[j].z + fmaf(pv[j].x, lw0.z, fmaf(pv[j].y, lw1.z, fmaf(pv[j].z, lw2.z, lb.z)))) * wv[j].z;
                r.w = (yv[j].w + fmaf(pv[j].x, lw0.w, fmaf(pv[j].y, lw1.w, fmaf(pv[j].z, lw2.w, lb.w)))) * wv[j].w;
                *((float4*)(out + XK_OFF + n_g * 1024 + (j * 64 + lane) * 4)) = r;
                racc.x += r.x; racc.y += r.y; racc.z += r.z; racc.w += r.w;
            }
            racc.x += __shfl_xor(racc.x, 16, 64); racc.y += __shfl_xor(racc.y, 16, 64);
            racc.z += __shfl_xor(racc.z, 16, 64); racc.w += __shfl_xor(racc.w, 16, 64);
            racc.x += __shfl_xor(racc.x, 32, 64); racc.y += __shfl_xor(racc.y, 32, 64);
            racc.z += __shfl_xor(racc.z, 32, 64); racc.w += __shfl_xor(racc.w, 32, 64);
            if (kh == 0)
                *((float4*)(out + OUT_OFF + n_g * 64 + c4 * 4)) = racc;
        }
    }
}

// ---------------- launch ----------------
extern "C" void kernel_launch(void* const* d_in, const int* in_sizes, int n_in,
                              void* d_out, int out_size, void* d_ws, size_t ws_size,
                              hipStream_t stream) {
    const float* p     = (const float*)d_in[0];
    const float* x     = (const float*)d_in[1];
    const int*   knn   = (const int*)d_in[2];
    const float* w01   = (const float*)d_in[3];
    const float* b01   = (const float*)d_in[4];
    const float* blW   = (const float*)d_in[5];
    const float* blB   = (const float*)d_in[6];
    const float* lp1_w = (const float*)d_in[7];
    const float* lp1_b = (const float*)d_in[8];
    const float* bnp_g = (const float*)d_in[9];
    const float* bnp_b = (const float*)d_in[10];
    const float* bnp_m = (const float*)d_in[11];
    const float* bnp_v = (const float*)d_in[12];
    const float* lp2_w = (const float*)d_in[13];
    const float* lp2_b = (const float*)d_in[14];
    const float* c2a_w = (const float*)d_in[15];
    const float* g2a   = (const float*)d_in[16];
    const float* b2a   = (const float*)d_in[17];
    const float* m2a   = (const float*)d_in[18];
    const float* v2a   = (const float*)d_in[19];
    const float* c2b_w = (const float*)d_in[20];
    const float* g2b   = (const float*)d_in[21];
    const float* b2b   = (const float*)d_in[22];
    const float* m2b   = (const float*)d_in[23];
    const float* v2b   = (const float*)d_in[24];
    const float* c2c_w = (const float*)d_in[25];
    const float* c2c_b = (const float*)d_in[26];
    const float* w03   = (const float*)d_in[27];
    const float* b03   = (const float*)d_in[28];
    float* ws  = (float*)d_ws;
    float* out = (float*)d_out;

    prep_small<<<1, 256, 0, stream>>>(blW, c2a_w, g2a, b2a, m2a, v2a,
                                      c2b_w, g2b, b2b, m2b, v2b,
                                      lp1_w, lp1_b, bnp_g, bnp_b, bnp_m, bnp_v, ws);
    y_gemm<<<(NPTS * 16) / 256, 256, 0, stream>>>(x, w03, b03, ws);
    pm_main<<<(NPTS * KNN) / 256, 256, 0, stream>>>(p, x, knn, w01, b01, blB,
                                                    lp2_w, lp2_b, c2c_w, c2c_b, ws, out);
}

// Round 3
// 740.005 us; speedup vs baseline: 1.2817x; 1.2817x over previous
//
#include <hip/hip_runtime.h>

// ---------------- problem constants ----------------
#define NPTS 100000
#define KNN  16

// workspace layout (float offsets)
#define Y_OFF    0            // y = x@w03+b03 : NPTS*64
#define BLWS_OFF 6400000      // symmetrized blW: 136 pairs x 16 o
#define C2AT_OFF 6402176      // c2a transposed+BN-folded: 64 x 32
#define T2A_OFF  6404224      // 64
#define C2BF_OFF 6404288      // c2b BN-folded: 64 x 8
#define T2B_OFF  6404800      // 8
#define AF_OFF   6404808      // linear_p folded 3x3
#define CF_OFF   6404817      // 3
#define M2_OFF   6404820      // folded shrink->c2a: 64 x {m0,m1,m2,m3} (float4/c)
#define XW_OFF   6405120      // xw = x @ w01[3:67] + b01 : NPTS*16 (optional)
#define WS_NEED_XW ((size_t)(XW_OFF + NPTS * 16) * 4)

// output layout (float offsets): (out, xk, knn_idx, p_r)
#define OUT_OFF  0
#define XK_OFF   6400000
#define IDXF_OFF 108800000
#define PR_OFF   110400000

#define EPSBN 1e-5f

__device__ __forceinline__ float4 f4fma(float a, float4 b, float4 c) {
    c.x = fmaf(a, b.x, c.x); c.y = fmaf(a, b.y, c.y);
    c.z = fmaf(a, b.z, c.z); c.w = fmaf(a, b.w, c.w);
    return c;
}
__device__ __forceinline__ float4 f4fma4(float4 a, float4 b, float4 c) {
    c.x = fmaf(a.x, b.x, c.x); c.y = fmaf(a.y, b.y, c.y);
    c.z = fmaf(a.z, b.z, c.z); c.w = fmaf(a.w, b.w, c.w);
    return c;
}

// ---------------- prep: fold BNs, symmetrize blW, fold shrink into c2a ----------------
__global__ __launch_bounds__(256) void prep_small(
    const float* __restrict__ blW,
    const float* __restrict__ c2a_w, const float* __restrict__ g2a, const float* __restrict__ b2a,
    const float* __restrict__ m2a, const float* __restrict__ v2a,
    const float* __restrict__ c2b_w, const float* __restrict__ g2b, const float* __restrict__ b2b,
    const float* __restrict__ m2b, const float* __restrict__ v2b,
    const float* __restrict__ lp1_w, const float* __restrict__ lp1_b,
    const float* __restrict__ bnp_g, const float* __restrict__ bnp_b,
    const float* __restrict__ bnp_m, const float* __restrict__ bnp_v,
    const float* __restrict__ lp2_w, const float* __restrict__ lp2_b,
    float* __restrict__ ws)
{
    const int t = threadIdx.x;
    float* blWs = ws + BLWS_OFF;
    for (int u = t; u < 136 * 16; u += 256) {
        const int pidx = u >> 4, o = u & 15;
        int i = 0, rem = pidx;
        while (rem >= 16 - i) { rem -= 16 - i; i++; }
        const int j = i + rem;
        float v = blW[o * 256 + i * 16 + j];
        if (j > i) v += blW[o * 256 + j * 16 + i];
        blWs[pidx * 16 + o] = v;
    }
    float* c2aT = ws + C2AT_OFF;
    for (int u = t; u < 64 * 32; u += 256) {
        const int c = u >> 5, d = u & 31;
        const float f = g2a[c] / sqrtf(v2a[c] + EPSBN);
        c2aT[c * 32 + d] = c2a_w[d * 64 + c] * f;
    }
    if (t < 64) {
        const float f = g2a[t] / sqrtf(v2a[t] + EPSBN);
        (ws + T2A_OFF)[t] = b2a[t] - m2a[t] * f;
    }
    float* c2bf = ws + C2BF_OFF;
    for (int u = t; u < 64 * 8; u += 256) {
        const int s = u & 7;
        const float f = g2b[s] / sqrtf(v2b[s] + EPSBN);
        c2bf[u] = c2b_w[u] * f;
    }
    if (t < 8) {
        const float f = g2b[t] / sqrtf(v2b[t] + EPSBN);
        (ws + T2B_OFF)[t] = b2b[t] - m2b[t] * f;
    }
    if (t < 9) {
        const int j = t % 3;
        const float f = bnp_g[j] / sqrtf(bnp_v[j] + EPSBN);
        (ws + AF_OFF)[t] = lp1_w[t] * f;
    }
    if (t < 3) {
        const float f = bnp_g[t] / sqrtf(bnp_v[t] + EPSBN);
        (ws + CF_OFF)[t] = (lp1_b[t] - bnp_m[t]) * f + bnp_b[t];
    }
    __syncthreads();
    // fold shrink (affine in pe) through c2a's sh-half:
    // shrink[t] = pe·S[:,t] + sb[t];  act_sh[c] = pe·M2[:,c] + (t2a[c] + sb·c2aT_sh[c])
    if (t < 64) {
        float m0 = 0.f, m1 = 0.f, m2 = 0.f, m3 = ws[T2A_OFF + t];
        for (int tt = 0; tt < 16; tt++) {
            const float w = ws[C2AT_OFF + t * 32 + 16 + tt];
            const float s0 = lp2_w[tt]       + lp2_w[16 + tt]  + lp2_w[32 + tt]  + lp2_w[48 + tt];
            const float s1 = lp2_w[64 + tt]  + lp2_w[80 + tt]  + lp2_w[96 + tt]  + lp2_w[112 + tt];
            const float s2 = lp2_w[128 + tt] + lp2_w[144 + tt] + lp2_w[160 + tt] + lp2_w[176 + tt];
            const float sbt = lp2_b[tt] + lp2_b[16 + tt] + lp2_b[32 + tt] + lp2_b[48 + tt];
            m0 = fmaf(s0, w, m0); m1 = fmaf(s1, w, m1);
            m2 = fmaf(s2, w, m2); m3 = fmaf(sbt, w, m3);
        }
        ws[M2_OFF + t * 4 + 0] = m0;
        ws[M2_OFF + t * 4 + 1] = m1;
        ws[M2_OFF + t * 4 + 2] = m2;
        ws[M2_OFF + t * 4 + 3] = m3;
    }
}

// ---------------- y = x @ w03 + b03  (one thread per (n, c4)) ----------------
__global__ __launch_bounds__(256) void y_gemm(
    const float* __restrict__ x, const float* __restrict__ w03,
    const float* __restrict__ b03, float* __restrict__ ws)
{
    const int tid = blockIdx.x * 256 + threadIdx.x;
    const int n = tid >> 4, c4 = tid & 15;
    const float4* __restrict__ x4 = (const float4*)x;
    const float4* __restrict__ w4 = (const float4*)w03;
    float4 acc = ((const float4*)b03)[c4];
    #pragma unroll 4
    for (int d4 = 0; d4 < 16; d4++) {
        const float4 xq = x4[n * 16 + d4];
        const float xs[4] = {xq.x, xq.y, xq.z, xq.w};
        #pragma unroll
        for (int e = 0; e < 4; e++) {
            const float4 wq = w4[(d4 * 4 + e) * 16 + c4];
            acc.x = fmaf(xs[e], wq.x, acc.x);
            acc.y = fmaf(xs[e], wq.y, acc.y);
            acc.z = fmaf(xs[e], wq.z, acc.z);
            acc.w = fmaf(xs[e], wq.w, acc.w);
        }
    }
    ((float4*)(ws + Y_OFF))[n * 16 + c4] = acc;
}

// ---------------- xw = x @ w01[3:67] + b01  (one thread per (n, c)) ----------------
__global__ __launch_bounds__(256) void xw_gemm(
    const float* __restrict__ x, const float* __restrict__ w01,
    const float* __restrict__ b01, float* __restrict__ ws)
{
    const int tid = blockIdx.x * 256 + threadIdx.x;
    const int n = tid >> 4, c = tid & 15;
    const float4* __restrict__ x4 = (const float4*)x;
    float acc = b01[c];
    #pragma unroll 4
    for (int d4 = 0; d4 < 16; d4++) {
        const float4 xq = x4[n * 16 + d4];
        acc = fmaf(xq.x, w01[(3 + d4 * 4 + 0) * 16 + c], acc);
        acc = fmaf(xq.y, w01[(3 + d4 * 4 + 1) * 16 + c], acc);
        acc = fmaf(xq.z, w01[(3 + d4 * 4 + 2) * 16 + c], acc);
        acc = fmaf(xq.w, w01[(3 + d4 * 4 + 3) * 16 + c], acc);
    }
    ws[XW_OFF + tid] = acc;
}

// ---------------- main fused kernel: one thread per (n,k) ----------------
template <bool USE_XW>
__global__ __launch_bounds__(256) void pm_main(
    const float* __restrict__ p, const float* __restrict__ x,
    const int* __restrict__ knn,
    const float* __restrict__ w01, const float* __restrict__ b01,
    const float* __restrict__ blB,
    const float* __restrict__ lp2_w, const float* __restrict__ lp2_b,
    const float* __restrict__ c2c_w, const float* __restrict__ c2c_b,
    const float* __restrict__ ws, float* __restrict__ out)
{
    __shared__ float meta[256][12];      // per-(n,k) state for phase-5 remap

    const int tid = blockIdx.x * 256 + threadIdx.x;
    const int n = tid >> 4;
    const int idx = knn[tid];

    const float prx = p[idx * 3 + 0] - p[n * 3 + 0];
    const float pry = p[idx * 3 + 1] - p[n * 3 + 1];
    const float prz = p[idx * 3 + 2] - p[n * 3 + 2];
    out[IDXF_OFF + tid] = (float)idx;
    out[PR_OFF + tid * 3 + 0] = prx;
    out[PR_OFF + tid * 3 + 1] = pry;
    out[PR_OFF + tid * 3 + 2] = prz;

    const float4* __restrict__ w01_4 = (const float4*)w01;   // [67][16] rows, 4 quads/row

    // ---- phase 1: h = relu([p_r, x[idx]] @ w01 + b01) ----
    float4 hq[4];
    if constexpr (USE_XW) {
        const float4* __restrict__ xw4 = (const float4*)(ws + XW_OFF);
        #pragma unroll
        for (int t4 = 0; t4 < 4; t4++) hq[t4] = xw4[idx * 4 + t4];
    } else {
        const float4* b01_4 = (const float4*)b01;
        #pragma unroll
        for (int t4 = 0; t4 < 4; t4++) hq[t4] = b01_4[t4];
        const float4* __restrict__ x4 = (const float4*)x;
        #pragma unroll 4
        for (int c4 = 0; c4 < 16; c4++) {
            const float4 xq = x4[idx * 16 + c4];
            const float xs[4] = {xq.x, xq.y, xq.z, xq.w};
            #pragma unroll
            for (int e = 0; e < 4; e++) {
                const int cc = 3 + c4 * 4 + e;
                const float xv = xs[e];
                #pragma unroll
                for (int t4 = 0; t4 < 4; t4++) hq[t4] = f4fma(xv, w01_4[cc * 4 + t4], hq[t4]);
            }
        }
    }
    {
        const float pr3[3] = {prx, pry, prz};
        #pragma unroll
        for (int c = 0; c < 3; c++) {
            const float xv = pr3[c];
            #pragma unroll
            for (int t4 = 0; t4 < 4; t4++) hq[t4] = f4fma(xv, w01_4[c * 4 + t4], hq[t4]);
        }
    }
    float h[16];
    #pragma unroll
    for (int t4 = 0; t4 < 4; t4++) {
        h[4 * t4 + 0] = fmaxf(hq[t4].x, 0.f);
        h[4 * t4 + 1] = fmaxf(hq[t4].y, 0.f);
        h[4 * t4 + 2] = fmaxf(hq[t4].z, 0.f);
        h[4 * t4 + 3] = fmaxf(hq[t4].w, 0.f);
    }

    // ---- phase 2: energy[o] = sum_{i<=j} h_i h_j * blWs[(i,j)][o] + blB ----
    float4 e4[4];
    {
        const float4* blB4 = (const float4*)blB;
        #pragma unroll
        for (int t4 = 0; t4 < 4; t4++) e4[t4] = blB4[t4];
    }
    {
        const float4* __restrict__ blws4 = (const float4*)(ws + BLWS_OFF);
        int pidx = 0;
        #pragma unroll
        for (int i = 0; i < 16; i++) {
            #pragma unroll
            for (int j = i; j < 16; j++) {
                const float u = h[i] * h[j];
                #pragma unroll
                for (int t4 = 0; t4 < 4; t4++) e4[t4] = f4fma(u, blws4[pidx * 4 + t4], e4[t4]);
                pidx++;
            }
        }
    }

    // ---- phase 3: folded linear_p (pe only; shrink folded into M2) ----
    float pe0, pe1, pe2;
    {
        const float* Af = ws + AF_OFF;
        const float* cf = ws + CF_OFF;
        pe0 = fmaxf(fmaf(prx, Af[0], fmaf(pry, Af[3], fmaf(prz, Af[6], cf[0]))), 0.f);
        pe1 = fmaxf(fmaf(prx, Af[1], fmaf(pry, Af[4], fmaf(prz, Af[7], cf[1]))), 0.f);
        pe2 = fmaxf(fmaf(prx, Af[2], fmaf(pry, Af[5], fmaf(prz, Af[8], cf[2]))), 0.f);
    }

    // ---- phase 4: c2a(BN,relu) -> c2b(BN,relu) -> c2c -> softmax over k ----
    float4 s4[2];
    {
        const float4* t2b4 = (const float4*)(ws + T2B_OFF);
        s4[0] = t2b4[0]; s4[1] = t2b4[1];
    }
    {
        const float4* __restrict__ c2aT4 = (const float4*)(ws + C2AT_OFF);
        const float4* __restrict__ c2bf4 = (const float4*)(ws + C2BF_OFF);
        const float4* __restrict__ m2_4  = (const float4*)(ws + M2_OFF);
        #pragma unroll 2
        for (int c = 0; c < 64; c++) {
            const float4* wr = c2aT4 + c * 8;         // energy half: quads 0..3
            float4 a4 = make_float4(0.f, 0.f, 0.f, 0.f);
            #pragma unroll
            for (int q = 0; q < 4; q++) a4 = f4fma4(e4[q], wr[q], a4);
            const float4 m = m2_4[c];
            const float hc = fmaxf(a4.x + a4.y + a4.z + a4.w
                                   + fmaf(pe0, m.x, fmaf(pe1, m.y, fmaf(pe2, m.z, m.w))), 0.f);
            const float4* br = c2bf4 + c * 2;
            s4[0] = f4fma(hc, br[0], s4[0]);
            s4[1] = f4fma(hc, br[1], s4[1]);
        }
    }
    float h2b[8];
    h2b[0] = fmaxf(s4[0].x, 0.f); h2b[1] = fmaxf(s4[0].y, 0.f);
    h2b[2] = fmaxf(s4[0].z, 0.f); h2b[3] = fmaxf(s4[0].w, 0.f);
    h2b[4] = fmaxf(s4[1].x, 0.f); h2b[5] = fmaxf(s4[1].y, 0.f);
    h2b[6] = fmaxf(s4[1].z, 0.f); h2b[7] = fmaxf(s4[1].w, 0.f);
    float2 l2[4];
    {
        const float2* cb2 = (const float2*)c2c_b;
        #pragma unroll
        for (int t = 0; t < 4; t++) l2[t] = cb2[t];
        const float2* c2c2 = (const float2*)c2c_w;
        #pragma unroll
        for (int s = 0; s < 8; s++) {
            const float hv = h2b[s];
            #pragma unroll
            for (int t = 0; t < 4; t++) {
                const float2 w2 = c2c2[s * 4 + t];
                l2[t].x = fmaf(hv, w2.x, l2[t].x);
                l2[t].y = fmaf(hv, w2.y, l2[t].y);
            }
        }
    }
    float wgt[8];
    #pragma unroll
    for (int s = 0; s < 8; s++) {
        const float l = (s & 1) ? l2[s >> 1].y : l2[s >> 1].x;
        float m = l;
        m = fmaxf(m, __shfl_xor(m, 1, 64));
        m = fmaxf(m, __shfl_xor(m, 2, 64));
        m = fmaxf(m, __shfl_xor(m, 4, 64));
        m = fmaxf(m, __shfl_xor(m, 8, 64));
        const float ex = __expf(l - m);
        float sm = ex;
        sm += __shfl_xor(sm, 1, 64);
        sm += __shfl_xor(sm, 2, 64);
        sm += __shfl_xor(sm, 4, 64);
        sm += __shfl_xor(sm, 8, 64);
        wgt[s] = ex / sm;
    }

    // ---- phase 4.5: publish per-(n,k) state ----
    {
        float4* m4 = (float4*)&meta[threadIdx.x][0];
        m4[0] = make_float4(wgt[0], wgt[1], wgt[2], wgt[3]);
        m4[1] = make_float4(wgt[4], wgt[5], wgt[6], wgt[7]);
        m4[2] = make_float4(pe0, pe1, pe2, __int_as_float(idx));
    }
    __syncthreads();

    // ---- phase 5 (remapped, batched loads): lane l owns (k = j*4 + l>>4, c4 = l&15) ----
    {
        const int lane = threadIdx.x & 63;
        const int waveBase = threadIdx.x & 192;
        const int c4 = lane & 15;
        const int kh = lane >> 4;
        const float4 lw0 = ((const float4*)lp2_w)[c4];
        const float4 lw1 = ((const float4*)lp2_w)[16 + c4];
        const float4 lw2 = ((const float4*)lp2_w)[32 + c4];
        const float4 lb  = ((const float4*)lp2_b)[c4];
        const float4* __restrict__ y4 = (const float4*)(ws + Y_OFF);
        const int nBase = blockIdx.x * 16 + (waveBase >> 4);
        const int wsel = c4 & 1;
        for (int g = 0; g < 4; g++) {
            const int n_g = nBase + g;
            float4 wv[4], pv[4];
            #pragma unroll
            for (int j = 0; j < 4; j++) {
                const int s = waveBase + g * 16 + j * 4 + kh;
                wv[j] = *((const float4*)&meta[s][0] + wsel);
                pv[j] = *((const float4*)&meta[s][0] + 2);
            }
            float4 yv[4];
            #pragma unroll
            for (int j = 0; j < 4; j++)
                yv[j] = y4[__float_as_int(pv[j].w) * 16 + c4];
            float4 racc = make_float4(0.f, 0.f, 0.f, 0.f);
            #pragma unroll
            for (int j = 0; j < 4; j++) {
                float4 r;
                r.x = (yv[j].x + fmaf(pv[j].x, lw0.x, fmaf(pv[j].y, lw1.x, fmaf(pv[j].z, lw2.x, lb.x)))) * wv[j].x;
                r.y = (yv[j].y + fmaf(pv[j].x, lw0.y, fmaf(pv[j].y, lw1.y, fmaf(pv[j].z, lw2.y, lb.y)))) * wv[j].y;
                r.z = (yv[j].z + fmaf(pv[j].x, lw0.z, fmaf(pv[j].y, lw1.z, fmaf(pv[j].z, lw2.z, lb.z)))) * wv[j].z;
                r.w = (yv[j].w + fmaf(pv[j].x, lw0.w, fmaf(pv[j].y, lw1.w, fmaf(pv[j].z, lw2.w, lb.w)))) * wv[j].w;
                *((float4*)(out + XK_OFF + n_g * 1024 + (j * 64 + lane) * 4)) = r;
                racc.x += r.x; racc.y += r.y; racc.z += r.z; racc.w += r.w;
            }
            racc.x += __shfl_xor(racc.x, 16, 64); racc.y += __shfl_xor(racc.y, 16, 64);
            racc.z += __shfl_xor(racc.z, 16, 64); racc.w += __shfl_xor(racc.w, 16, 64);
            racc.x += __shfl_xor(racc.x, 32, 64); racc.y += __shfl_xor(racc.y, 32, 64);
            racc.z += __shfl_xor(racc.z, 32, 64); racc.w += __shfl_xor(racc.w, 32, 64);
            if (kh == 0)
                *((float4*)(out + OUT_OFF + n_g * 64 + c4 * 4)) = racc;
        }
    }
}

// ---------------- launch ----------------
extern "C" void kernel_launch(void* const* d_in, const int* in_sizes, int n_in,
                              void* d_out, int out_size, void* d_ws, size_t ws_size,
                              hipStream_t stream) {
    const float* p     = (const float*)d_in[0];
    const float* x     = (const float*)d_in[1];
    const int*   knn   = (const int*)d_in[2];
    const float* w01   = (const float*)d_in[3];
    const float* b01   = (const float*)d_in[4];
    const float* blW   = (const float*)d_in[5];
    const float* blB   = (const float*)d_in[6];
    const float* lp1_w = (const float*)d_in[7];
    const float* lp1_b = (const float*)d_in[8];
    const float* bnp_g = (const float*)d_in[9];
    const float* bnp_b = (const float*)d_in[10];
    const float* bnp_m = (const float*)d_in[11];
    const float* bnp_v = (const float*)d_in[12];
    const float* lp2_w = (const float*)d_in[13];
    const float* lp2_b = (const float*)d_in[14];
    const float* c2a_w = (const float*)d_in[15];
    const float* g2a   = (const float*)d_in[16];
    const float* b2a   = (const float*)d_in[17];
    const float* m2a   = (const float*)d_in[18];
    const float* v2a   = (const float*)d_in[19];
    const float* c2b_w = (const float*)d_in[20];
    const float* g2b   = (const float*)d_in[21];
    const float* b2b   = (const float*)d_in[22];
    const float* m2b   = (const float*)d_in[23];
    const float* v2b   = (const float*)d_in[24];
    const float* c2c_w = (const float*)d_in[25];
    const float* c2c_b = (const float*)d_in[26];
    const float* w03   = (const float*)d_in[27];
    const float* b03   = (const float*)d_in[28];
    float* ws  = (float*)d_ws;
    float* out = (float*)d_out;

    prep_small<<<1, 256, 0, stream>>>(blW, c2a_w, g2a, b2a, m2a, v2a,
                                      c2b_w, g2b, b2b, m2b, v2b,
                                      lp1_w, lp1_b, bnp_g, bnp_b, bnp_m, bnp_v,
                                      lp2_w, lp2_b, ws);
    y_gemm<<<(NPTS * 16) / 256, 256, 0, stream>>>(x, w03, b03, ws);
    if (ws_size >= WS_NEED_XW) {
        xw_gemm<<<(NPTS * 16) / 256, 256, 0, stream>>>(x, w01, b01, ws);
        pm_main<true><<<(NPTS * KNN) / 256, 256, 0, stream>>>(p, x, knn, w01, b01, blB,
                                                              lp2_w, lp2_b, c2c_w, c2c_b, ws, out);
    } else {
        pm_main<false><<<(NPTS * KNN) / 256, 256, 0, stream>>>(p, x, knn, w01, b01, blB,
                                                               lp2_w, lp2_b, c2c_w, c2c_b, ws, out);
    }
}